// Round 10
// baseline (30.746 us; speedup 1.0000x reference)
//
#include <hip/hip_runtime.h>
#include <math.h>

// Problem constants (from reference setup_inputs)
#define BB 512
#define TT 8000
#define HALF 4000       // elements per block (half a batch)
#define NACC 13         // 3 SP + 9 XT + 1 msum (padded to 16 in records)

__device__ __forceinline__ void accum_elem(float acc[NACC], float m,
                                           float x0, float x1, float x2,
                                           float t0, float t1, float t2) {
    acc[12] += m;
    float x[3] = {x0, x1, x2};
    float t[3] = {t0, t1, t2};
    #pragma unroll
    for (int i = 0; i < 3; i++) {
        float xi = x[i];
        float sp = fmaxf(xi, 0.0f) + __logf(1.0f + __expf(-fabsf(xi)));
        acc[i] = fmaf(m, sp, acc[i]);
        float mx = m * xi;
        #pragma unroll
        for (int j = 0; j < 3; j++)
            acc[3 + i*3 + j] = fmaf(mx, t[j], acc[3 + i*3 + j]);
    }
}

// Kernel 1: 1024 blocks x 256 threads; block = (batch b, half h); 16 elems
// per thread in 2 groups of 8. Each group: 24 independent loads (8 pred x3,
// 8 tgt x3, 8 mask x1), then sched_barrier(0) pins the load cluster BEFORE
// its compute -> compiler must keep ~56 landing VGPRs, all 24 loads in
// flight (R9 showed it otherwise re-serializes to 40 VGPR).
__global__ __launch_bounds__(256) void pit_partial(
        const float* __restrict__ pred,
        const float* __restrict__ tgt,
        const float* __restrict__ mask,
        float* __restrict__ bpart) {
    __shared__ float red[4][16];

    int blk = blockIdx.x;
    int b = blk >> 1, h = blk & 1;
    int base = h * HALF;
    const float* pp = pred + (size_t)b * TT * 3;
    const float* tp = tgt  + (size_t)b * TT * 3;
    const float* mp = mask + (size_t)b * TT;

    int tid = threadIdx.x;
    float acc[NACC];
    #pragma unroll
    for (int k = 0; k < NACC; k++) acc[k] = 0.0f;

    #pragma unroll
    for (int g = 0; g < 2; g++) {
        float3 X[8], G[8]; float M[8];
        #pragma unroll
        for (int u = 0; u < 8; u++) {
            int t = base + tid + (g * 8 + u) * 256;     // < base+4096
            int hi = base + HALF;
            int tc_ = t < hi ? t : hi - 1;              // clamp, in-bounds
            X[u] = *(const float3*)(pp + 3 * (size_t)tc_);
            G[u] = *(const float3*)(tp + 3 * (size_t)tc_);
            float m = mp[tc_];
            M[u] = (t < hi) ? m : 0.0f;
        }
        __builtin_amdgcn_sched_barrier(0);   // loads stay above, in flight
        #pragma unroll
        for (int u = 0; u < 8; u++)
            accum_elem(acc, M[u], X[u].x, X[u].y, X[u].z,
                       G[u].x, G[u].y, G[u].z);
    }

    // f32 butterfly reduce across the wave.
    #pragma unroll
    for (int k = 0; k < NACC; k++) {
        float v = acc[k];
        #pragma unroll
        for (int o = 32; o > 0; o >>= 1) v += __shfl_xor(v, o, 64);
        acc[k] = v;
    }

    int lane = tid & 63, w = tid >> 6;
    if (lane == 0) {
        #pragma unroll
        for (int k = 0; k < NACC; k++) red[w][k] = acc[k];
        red[w][13] = 0.0f; red[w][14] = 0.0f; red[w][15] = 0.0f;
    }
    __syncthreads();
    if (tid < 16) {
        float s = red[0][tid] + red[1][tid] + red[2][tid] + red[3][tid];
        bpart[(size_t)blk * 16 + tid] = s;   // coalesced 64 B record
    }
}

// Kernel 2 (fused epilogue, single block of 512): thread b sums its 2 half
// records (double), builds cost, argmin over 6 perms -> out[1+b]; then
// butterfly-mean over the 512 best values -> out[0]. Reads 64 KB total.
__global__ __launch_bounds__(512) void pit_final(
        const float* __restrict__ bpart, float* __restrict__ out) {
    __shared__ double sd[8];
    int b = threadIdx.x;

    double a[NACC];
    const float* r = bpart + (size_t)b * 32;   // 2 records x 16 floats
    #pragma unroll
    for (int k = 0; k < NACC; k++)
        a[k] = (double)r[k] + (double)r[16 + k];

    double msum = a[12] + 1e-14;
    double cost[3][3];
    #pragma unroll
    for (int i = 0; i < 3; i++)
        #pragma unroll
        for (int j = 0; j < 3; j++)
            cost[i][j] = (a[i] - a[3 + i*3 + j]) / msum;

    const int perms[6][3] = {{0,1,2},{0,2,1},{1,0,2},{1,2,0},{2,0,1},{2,1,0}};
    double best = 1e300; int bidx = 0;
    #pragma unroll
    for (int p = 0; p < 6; p++) {
        double v = (cost[0][perms[p][0]] + cost[1][perms[p][1]] +
                    cost[2][perms[p][2]]) / 3.0;
        if (v < best) { best = v; bidx = p; }
    }
    out[1 + b] = (float)bidx;

    // Mean of best over 512 batches (8 waves).
    double v = best;
    #pragma unroll
    for (int o = 32; o > 0; o >>= 1) v += __shfl_down(v, o, 64);
    int lane = b & 63, w = b >> 6;
    if (lane == 0) sd[w] = v;
    __syncthreads();
    if (b == 0) {
        double s = 0.0;
        #pragma unroll
        for (int i = 0; i < 8; i++) s += sd[i];
        out[0] = (float)(s / (double)BB);
    }
}

extern "C" void kernel_launch(void* const* d_in, const int* in_sizes, int n_in,
                              void* d_out, int out_size, void* d_ws, size_t ws_size,
                              hipStream_t stream) {
    const float* pred = (const float*)d_in[0];
    const float* tgt  = (const float*)d_in[1];
    const float* mask = (const float*)d_in[2];
    float* out = (float*)d_out;
    float* bpart = (float*)d_ws;   // 1024*16 floats = 64 KB

    pit_partial<<<BB * 2, 256, 0, stream>>>(pred, tgt, mask, bpart);
    pit_final<<<1, 512, 0, stream>>>(bpart, out);
}

// Round 12
// 27.786 us; speedup vs baseline: 1.1065x; 1.1065x over previous
//
#include <hip/hip_runtime.h>
#include <math.h>

// Problem constants (from reference setup_inputs)
#define BB 512
#define TT 8000
#define HALF 4000       // elements per block (half a batch)
#define NACC 13         // 3 SP + 9 XT + 1 msum (padded to 16 in records)

__device__ __forceinline__ void accum_elem(float acc[NACC], float m,
                                           float x0, float x1, float x2,
                                           float t0, float t1, float t2) {
    acc[12] += m;
    float x[3] = {x0, x1, x2};
    float t[3] = {t0, t1, t2};
    #pragma unroll
    for (int i = 0; i < 3; i++) {
        float xi = x[i];
        float sp = fmaxf(xi, 0.0f) + __logf(1.0f + __expf(-fabsf(xi)));
        acc[i] = fmaf(m, sp, acc[i]);
        float mx = m * xi;
        #pragma unroll
        for (int j = 0; j < 3; j++)
            acc[3 + i*3 + j] = fmaf(mx, t[j], acc[3 + i*3 + j]);
    }
}

// Kernel 1 (R9, best measured: 27.9 us total): 1024 blocks x 256 threads;
// block = (batch b, half h), 16 elems/thread in 4 groups of {load 4,
// accumulate 4}, dense dwordx3 loads; f32 wave butterfly; 64 B record/block.
__global__ __launch_bounds__(256) void pit_partial(
        const float* __restrict__ pred,
        const float* __restrict__ tgt,
        const float* __restrict__ mask,
        float* __restrict__ bpart) {
    __shared__ float red[4][16];

    int blk = blockIdx.x;
    int b = blk >> 1, h = blk & 1;
    int base = h * HALF;
    const float* pp = pred + (size_t)b * TT * 3;
    const float* tp = tgt  + (size_t)b * TT * 3;
    const float* mp = mask + (size_t)b * TT;

    int tid = threadIdx.x;
    float acc[NACC];
    #pragma unroll
    for (int k = 0; k < NACC; k++) acc[k] = 0.0f;

    #pragma unroll
    for (int g = 0; g < 4; g++) {
        float3 X[4], G[4]; float M[4];
        #pragma unroll
        for (int u = 0; u < 4; u++) {
            int t = base + tid + (g * 4 + u) * 256;     // < base+4096
            int hi = base + HALF;
            int tc_ = t < hi ? t : hi - 1;              // clamp, in-bounds
            X[u] = *(const float3*)(pp + 3 * (size_t)tc_);
            G[u] = *(const float3*)(tp + 3 * (size_t)tc_);
            float m = mp[tc_];
            M[u] = (t < hi) ? m : 0.0f;
        }
        #pragma unroll
        for (int u = 0; u < 4; u++)
            accum_elem(acc, M[u], X[u].x, X[u].y, X[u].z,
                       G[u].x, G[u].y, G[u].z);
    }

    // f32 butterfly reduce across the wave.
    #pragma unroll
    for (int k = 0; k < NACC; k++) {
        float v = acc[k];
        #pragma unroll
        for (int o = 32; o > 0; o >>= 1) v += __shfl_xor(v, o, 64);
        acc[k] = v;
    }

    int lane = tid & 63, w = tid >> 6;
    if (lane == 0) {
        #pragma unroll
        for (int k = 0; k < NACC; k++) red[w][k] = acc[k];
        red[w][13] = 0.0f; red[w][14] = 0.0f; red[w][15] = 0.0f;
    }
    __syncthreads();
    if (tid < 16) {
        float s = red[0][tid] + red[1][tid] + red[2][tid] + red[3][tid];
        bpart[(size_t)blk * 16 + tid] = s;   // coalesced 64 B record
    }
}

// Kernel 2 (fused epilogue, single block of 512): thread b sums its 2 half
// records (double), builds cost, argmin over 6 perms -> out[1+b]; then
// butterfly-mean over the 512 best values -> out[0]. Reads 64 KB total.
__global__ __launch_bounds__(512) void pit_final(
        const float* __restrict__ bpart, float* __restrict__ out) {
    __shared__ double sd[8];
    int b = threadIdx.x;

    double a[NACC];
    const float* r = bpart + (size_t)b * 32;   // 2 records x 16 floats
    #pragma unroll
    for (int k = 0; k < NACC; k++)
        a[k] = (double)r[k] + (double)r[16 + k];

    double msum = a[12] + 1e-14;
    double cost[3][3];
    #pragma unroll
    for (int i = 0; i < 3; i++)
        #pragma unroll
        for (int j = 0; j < 3; j++)
            cost[i][j] = (a[i] - a[3 + i*3 + j]) / msum;

    const int perms[6][3] = {{0,1,2},{0,2,1},{1,0,2},{1,2,0},{2,0,1},{2,1,0}};
    double best = 1e300; int bidx = 0;
    #pragma unroll
    for (int p = 0; p < 6; p++) {
        double v = (cost[0][perms[p][0]] + cost[1][perms[p][1]] +
                    cost[2][perms[p][2]]) / 3.0;
        if (v < best) { best = v; bidx = p; }
    }
    out[1 + b] = (float)bidx;

    // Mean of best over 512 batches (8 waves).
    double v = best;
    #pragma unroll
    for (int o = 32; o > 0; o >>= 1) v += __shfl_down(v, o, 64);
    int lane = b & 63, w = b >> 6;
    if (lane == 0) sd[w] = v;
    __syncthreads();
    if (b == 0) {
        double s = 0.0;
        #pragma unroll
        for (int i = 0; i < 8; i++) s += sd[i];
        out[0] = (float)(s / (double)BB);
    }
}

extern "C" void kernel_launch(void* const* d_in, const int* in_sizes, int n_in,
                              void* d_out, int out_size, void* d_ws, size_t ws_size,
                              hipStream_t stream) {
    const float* pred = (const float*)d_in[0];
    const float* tgt  = (const float*)d_in[1];
    const float* mask = (const float*)d_in[2];
    float* out = (float*)d_out;
    float* bpart = (float*)d_ws;   // 1024*16 floats = 64 KB

    pit_partial<<<BB * 2, 256, 0, stream>>>(pred, tgt, mask, bpart);
    pit_final<<<1, 512, 0, stream>>>(bpart, out);
}